// Round 1
// baseline (326.318 us; speedup 1.0000x reference)
//
#include <hip/hip_runtime.h>
#include <stdint.h>

typedef unsigned int u32;
typedef unsigned short u16;

#define NROWS 100000
#define DIM 512
#define TWOD 1024
#define HDIM 1024
#define OUTF 250
#define NSEG 256
#define LNEPS 1e-5f

typedef __bf16 bf16_t;
typedef bf16_t bf16x8 __attribute__((ext_vector_type(8)));
typedef float f32x4 __attribute__((ext_vector_type(4)));

__device__ inline u16 f2bf(float f) {
    u32 u = __float_as_uint(f);
    u = (u + 0x7FFFu + ((u >> 16) & 1u)) >> 16;
    return (u16)u;
}
__device__ inline u32 pack2(float a, float b) {
    return (u32)f2bf(a) | ((u32)f2bf(b) << 16);
}

__device__ inline int lower_bound(const int* __restrict__ a, int n, int v) {
    int lo = 0, hi = n;
    while (lo < hi) {
        int m = (lo + hi) >> 1;
        if (a[m] < v) lo = m + 1; else hi = m;
    }
    return lo;
}

// ---------------------------------------------------------------------------
// Kernel 0: convert gW1 [1024][512] fp32 -> bf16 fragments in MFMA-linear order
// Wf layout: [ks(16)][nt(64)][lane(64)] x 16B ; element (lane,j):
//   n = nt*16 + (lane&15), k = ks*32 + (lane>>4)*8 + j
// ---------------------------------------------------------------------------
__global__ __launch_bounds__(256) void k_wconv(const float* __restrict__ gW1,
                                               u16* __restrict__ Wf) {
    int gid  = blockIdx.x * 256 + threadIdx.x;   // 0..65535
    int lane = gid & 63;
    int grp  = gid >> 6;                         // ks*64 + nt
    int ks   = grp >> 6, nt = grp & 63;
    int n    = nt * 16 + (lane & 15);
    int k0   = ks * 32 + ((lane >> 4) << 3);
    const float* src = gW1 + (size_t)n * DIM + k0;
    float4 f0 = *reinterpret_cast<const float4*>(src);
    float4 f1 = *reinterpret_cast<const float4*>(src + 4);
    uint4 val;
    val.x = pack2(f0.x, f0.y); val.y = pack2(f0.z, f0.w);
    val.z = pack2(f1.x, f1.y); val.w = pack2(f1.z, f1.w);
    reinterpret_cast<uint4*>(Wf)[gid] = val;
}

// ---------------------------------------------------------------------------
// Kernel 1: fused  gate[i] = relu(LN(x_i @ gW1.T + gb1)) . gW2 + gb2
// BM=32 rows/block, 8 waves, wave w owns cols [128w,128w+128)
// ---------------------------------------------------------------------------
#define BM 32
__global__ __launch_bounds__(512) void k_gate(
    const float* __restrict__ x, const u16* __restrict__ Wf,
    const float* __restrict__ gb1,
    const float* __restrict__ gln_g, const float* __restrict__ gln_b,
    const float* __restrict__ gW2, const float* __restrict__ gb2,
    float* __restrict__ gate)
{
    __shared__ __align__(16) u16 xlds[BM * DIM];   // 32KB, XOR-swizzled 16B units
    __shared__ float redS[8][BM];
    __shared__ float redQ[8][BM];
    __shared__ float meanArr[BM], rstdArr[BM];

    const int tid  = threadIdx.x;
    const int lane = tid & 63;
    const int w    = tid >> 6;          // wave 0..7
    const int l15  = lane & 15;
    const int g4   = lane >> 4;         // 0..3
    const int row0 = blockIdx.x * BM;

    // ---- stage x rows -> LDS bf16 (swizzled: unit u of row r at (u ^ (r&7)))
    #pragma unroll
    for (int uu = 0; uu < 4; ++uu) {
        int lu  = uu * 512 + tid;       // unit id 0..2047 (unit = 8 elements)
        int row = lu >> 6;
        int u   = lu & 63;
        const float* src = x + (size_t)(row0 + row) * DIM + u * 8;
        float4 f0 = *reinterpret_cast<const float4*>(src);
        float4 f1 = *reinterpret_cast<const float4*>(src + 4);
        uint4 val;
        val.x = pack2(f0.x, f0.y); val.y = pack2(f0.z, f0.w);
        val.z = pack2(f1.x, f1.y); val.w = pack2(f1.z, f1.w);
        int phys = row * DIM + ((u ^ (row & 7)) << 3);   // u16 units
        *reinterpret_cast<uint4*>(&xlds[phys]) = val;
    }
    __syncthreads();

    // ---- K loop: acc[m][t] covers rows 16m+(l>>4)*4+j , col 16*(8w+t)+(l&15)
    f32x4 acc[2][8];
    #pragma unroll
    for (int m = 0; m < 2; ++m)
        #pragma unroll
        for (int t = 0; t < 8; ++t)
            acc[m][t] = (f32x4){0.f, 0.f, 0.f, 0.f};

    const bf16x8* WfB = reinterpret_cast<const bf16x8*>(Wf);

    #pragma unroll 4
    for (int ks = 0; ks < 16; ++ks) {
        bf16x8 b[8];
        #pragma unroll
        for (int t = 0; t < 8; ++t) {
            int nt = w * 8 + t;
            b[t] = WfB[(ks * 64 + nt) * 64 + lane];
        }
        bf16x8 a[2];
        #pragma unroll
        for (int m = 0; m < 2; ++m) {
            int row  = m * 16 + l15;
            int u    = ks * 4 + g4;
            int phys = row * DIM + ((u ^ (row & 7)) << 3);
            a[m] = *reinterpret_cast<const bf16x8*>(&xlds[phys]);
        }
        #pragma unroll
        for (int m = 0; m < 2; ++m)
            #pragma unroll
            for (int t = 0; t < 8; ++t)
                acc[m][t] = __builtin_amdgcn_mfma_f32_16x16x32_bf16(a[m], b[t], acc[m][t], 0, 0, 0);
    }

    // ---- add gb1 bias (affects LN stats)
    float cbias[8];
    #pragma unroll
    for (int t = 0; t < 8; ++t) {
        int c = (w * 8 + t) * 16 + l15;
        cbias[t] = gb1[c];
    }
    #pragma unroll
    for (int m = 0; m < 2; ++m)
        #pragma unroll
        for (int t = 0; t < 8; ++t)
            #pragma unroll
            for (int j = 0; j < 4; ++j)
                acc[m][t][j] += cbias[t];

    // ---- per-row LN stats (sum, sumsq) over 1024 cols
    float s1[8], s2[8];
    #pragma unroll
    for (int i = 0; i < 8; ++i) { s1[i] = 0.f; s2[i] = 0.f; }
    #pragma unroll
    for (int m = 0; m < 2; ++m)
        #pragma unroll
        for (int t = 0; t < 8; ++t)
            #pragma unroll
            for (int j = 0; j < 4; ++j) {
                float v = acc[m][t][j];
                s1[m * 4 + j] += v;
                s2[m * 4 + j] += v * v;
            }
    #pragma unroll
    for (int off = 1; off < 16; off <<= 1) {
        #pragma unroll
        for (int i = 0; i < 8; ++i) {
            s1[i] += __shfl_xor(s1[i], off);
            s2[i] += __shfl_xor(s2[i], off);
        }
    }
    if (l15 == 0) {
        #pragma unroll
        for (int m = 0; m < 2; ++m)
            #pragma unroll
            for (int j = 0; j < 4; ++j) {
                int row = m * 16 + g4 * 4 + j;
                redS[w][row] = s1[m * 4 + j];
                redQ[w][row] = s2[m * 4 + j];
            }
    }
    __syncthreads();
    if (tid < BM) {
        float S1 = 0.f, S2 = 0.f;
        #pragma unroll
        for (int ww = 0; ww < 8; ++ww) { S1 += redS[ww][tid]; S2 += redQ[ww][tid]; }
        float mean = S1 * (1.0f / 1024.0f);
        float var  = S2 * (1.0f / 1024.0f) - mean * mean;
        meanArr[tid] = mean;
        rstdArr[tid] = rsqrtf(var + LNEPS);
    }
    __syncthreads();

    // ---- apply LN + relu + dot with gW2
    float cg[8], cb[8], cw[8];
    #pragma unroll
    for (int t = 0; t < 8; ++t) {
        int c = (w * 8 + t) * 16 + l15;
        cg[t] = gln_g[c]; cb[t] = gln_b[c]; cw[t] = gW2[c];
    }
    float mn[2][4], rs[2][4];
    #pragma unroll
    for (int m = 0; m < 2; ++m)
        #pragma unroll
        for (int j = 0; j < 4; ++j) {
            int row = m * 16 + g4 * 4 + j;
            mn[m][j] = meanArr[row];
            rs[m][j] = rstdArr[row];
        }
    float gp[8];
    #pragma unroll
    for (int i = 0; i < 8; ++i) gp[i] = 0.f;
    #pragma unroll
    for (int m = 0; m < 2; ++m)
        #pragma unroll
        for (int t = 0; t < 8; ++t)
            #pragma unroll
            for (int j = 0; j < 4; ++j) {
                float h = (acc[m][t][j] - mn[m][j]) * rs[m][j] * cg[t] + cb[t];
                h = fmaxf(h, 0.f);
                gp[m * 4 + j] += h * cw[t];
            }
    #pragma unroll
    for (int off = 1; off < 16; off <<= 1) {
        #pragma unroll
        for (int i = 0; i < 8; ++i) gp[i] += __shfl_xor(gp[i], off);
    }
    if (l15 == 0) {
        #pragma unroll
        for (int m = 0; m < 2; ++m)
            #pragma unroll
            for (int j = 0; j < 4; ++j) {
                int row = m * 16 + g4 * 4 + j;
                redS[w][row] = gp[m * 4 + j];
            }
    }
    __syncthreads();
    if (tid < BM) {
        float g = gb2[0];
        #pragma unroll
        for (int ww = 0; ww < 8; ++ww) g += redS[ww][tid];
        gate[row0 + tid] = g;
    }
}

// ---------------------------------------------------------------------------
// Kernel 2: per-segment max and sum(exp)
// ---------------------------------------------------------------------------
__global__ __launch_bounds__(256) void k_seg(const int* __restrict__ ids,
                                             const float* __restrict__ gate,
                                             float* __restrict__ segmax,
                                             float* __restrict__ segden) {
    int b = blockIdx.x, tid = threadIdx.x;
    int start = lower_bound(ids, NROWS, b);
    int end   = lower_bound(ids, NROWS, b + 1);
    __shared__ float sh[4];

    float lm = -INFINITY;
    for (int i = start + tid; i < end; i += 256) lm = fmaxf(lm, gate[i]);
    #pragma unroll
    for (int off = 32; off; off >>= 1) lm = fmaxf(lm, __shfl_xor(lm, off));
    if ((tid & 63) == 0) sh[tid >> 6] = lm;
    __syncthreads();
    float m = fmaxf(fmaxf(sh[0], sh[1]), fmaxf(sh[2], sh[3]));
    __syncthreads();

    float ls = 0.f;
    for (int i = start + tid; i < end; i += 256) ls += __expf(gate[i] - m);
    #pragma unroll
    for (int off = 32; off; off >>= 1) ls += __shfl_xor(ls, off);
    if ((tid & 63) == 0) sh[tid >> 6] = ls;
    __syncthreads();
    if (tid == 0) {
        segmax[b] = m;
        segden[b] = sh[0] + sh[1] + sh[2] + sh[3];
    }
}

// ---------------------------------------------------------------------------
// Kernel 3: pooled[b][d] = sum_i w_i * x[i][d]
// grid (4, 256) x 128 threads : block = (colchunk, segment)
// ---------------------------------------------------------------------------
__global__ __launch_bounds__(128) void k_pool(const int* __restrict__ ids,
                                              const float* __restrict__ gate,
                                              const float* __restrict__ x,
                                              const float* __restrict__ segmax,
                                              const float* __restrict__ segden,
                                              float* __restrict__ pooled) {
    int chunk = blockIdx.x, b = blockIdx.y, tid = threadIdx.x;
    int d = chunk * 128 + tid;
    int start = lower_bound(ids, NROWS, b);
    int end   = lower_bound(ids, NROWS, b + 1);
    float m   = segmax[b];
    float den = segden[b];
    float inv = (den > 0.f) ? 1.0f / den : 0.0f;
    float acc = 0.f;
    #pragma unroll 4
    for (int i = start; i < end; ++i) {
        float wgt = __expf(gate[i] - m) * inv;
        acc += wgt * x[(size_t)i * DIM + d];
    }
    pooled[b * DIM + d] = acc;
}

// ---------------------------------------------------------------------------
// Kernel 4: fused head: out=LN(pooled); z=relu(LN(out@mW1.T+mb1)); logits=z@mW2.T+mb2
// ---------------------------------------------------------------------------
__device__ inline float block_sum(float v, float* sh, int tid) {
    #pragma unroll
    for (int off = 32; off; off >>= 1) v += __shfl_xor(v, off);
    if ((tid & 63) == 0) sh[tid >> 6] = v;
    __syncthreads();
    float r = sh[0] + sh[1] + sh[2] + sh[3];
    __syncthreads();
    return r;
}

__global__ __launch_bounds__(256) void k_head(
    const float* __restrict__ pooled,
    const float* __restrict__ pn_g, const float* __restrict__ pn_b,
    const float* __restrict__ mW1, const float* __restrict__ mb1,
    const float* __restrict__ mln_g, const float* __restrict__ mln_b,
    const float* __restrict__ mW2, const float* __restrict__ mb2,
    float* __restrict__ logits)
{
    const int b = blockIdx.x, tid = threadIdx.x;
    __shared__ float outr[DIM];
    __shared__ float zr[HDIM];
    __shared__ float shred[4];

    float v0 = pooled[b * DIM + tid];
    float v1 = pooled[b * DIM + 256 + tid];
    float S = block_sum(v0 + v1, shred, tid);
    float Q = block_sum(v0 * v0 + v1 * v1, shred, tid);
    float mean = S * (1.0f / 512.0f);
    float rstd = rsqrtf(Q * (1.0f / 512.0f) - mean * mean + LNEPS);
    outr[tid]       = (v0 - mean) * rstd * pn_g[tid] + pn_b[tid];
    outr[tid + 256] = (v1 - mean) * rstd * pn_g[tid + 256] + pn_b[tid + 256];
    __syncthreads();

    float y[4];
    #pragma unroll
    for (int q = 0; q < 4; ++q) {
        int f = q * 256 + tid;
        const float4* wr = reinterpret_cast<const float4*>(mW1 + (size_t)f * DIM);
        float acc = 0.f;
        #pragma unroll 8
        for (int kk = 0; kk < 128; ++kk) {
            float4 wv = wr[kk];
            acc += wv.x * outr[kk * 4 + 0] + wv.y * outr[kk * 4 + 1]
                 + wv.z * outr[kk * 4 + 2] + wv.w * outr[kk * 4 + 3];
        }
        y[q] = acc + mb1[f];
    }
    float S2 = block_sum(y[0] + y[1] + y[2] + y[3], shred, tid);
    float Q2 = block_sum(y[0]*y[0] + y[1]*y[1] + y[2]*y[2] + y[3]*y[3], shred, tid);
    float mean2 = S2 * (1.0f / 1024.0f);
    float rstd2 = rsqrtf(Q2 * (1.0f / 1024.0f) - mean2 * mean2 + LNEPS);
    #pragma unroll
    for (int q = 0; q < 4; ++q) {
        int f = q * 256 + tid;
        zr[f] = fmaxf((y[q] - mean2) * rstd2 * mln_g[f] + mln_b[f], 0.f);
    }
    __syncthreads();
    if (tid < OUTF) {
        const float4* wr = reinterpret_cast<const float4*>(mW2 + (size_t)tid * HDIM);
        float acc = 0.f;
        #pragma unroll 8
        for (int kk = 0; kk < 256; ++kk) {
            float4 wv = wr[kk];
            acc += wv.x * zr[kk * 4 + 0] + wv.y * zr[kk * 4 + 1]
                 + wv.z * zr[kk * 4 + 2] + wv.w * zr[kk * 4 + 3];
        }
        logits[b * OUTF + tid] = acc + mb2[tid];
    }
}

// ---------------------------------------------------------------------------
extern "C" void kernel_launch(void* const* d_in, const int* in_sizes, int n_in,
                              void* d_out, int out_size, void* d_ws, size_t ws_size,
                              hipStream_t stream) {
    const float* x     = (const float*)d_in[0];
    const int*   ids   = (const int*)  d_in[1];
    const float* gW1   = (const float*)d_in[2];
    const float* gb1   = (const float*)d_in[3];
    const float* gln_g = (const float*)d_in[4];
    const float* gln_b = (const float*)d_in[5];
    const float* gW2   = (const float*)d_in[6];
    const float* gb2   = (const float*)d_in[7];
    const float* pn_g  = (const float*)d_in[8];
    const float* pn_b  = (const float*)d_in[9];
    const float* mW1   = (const float*)d_in[10];
    const float* mb1   = (const float*)d_in[11];
    const float* mln_g = (const float*)d_in[12];
    const float* mln_b = (const float*)d_in[13];
    const float* mW2   = (const float*)d_in[14];
    const float* mb2   = (const float*)d_in[15];
    float* logits = (float*)d_out;

    char* ws = (char*)d_ws;
    u16*   Wf     = (u16*)  (ws);                       // 1 MB
    float* gate   = (float*)(ws + (1 << 20));           // 400 KB
    float* segmax = (float*)(ws + (1 << 20) + 409600);  // 1 KB
    float* segden = segmax + 256;
    float* pooled = (float*)(ws + (1 << 20) + 409600 + 4096);  // 512 KB

    hipLaunchKernelGGL(k_wconv, dim3(256), dim3(256), 0, stream, gW1, Wf);
    hipLaunchKernelGGL(k_gate, dim3(NROWS / BM), dim3(512), 0, stream,
                       x, Wf, gb1, gln_g, gln_b, gW2, gb2, gate);
    hipLaunchKernelGGL(k_seg, dim3(NSEG), dim3(256), 0, stream, ids, gate, segmax, segden);
    hipLaunchKernelGGL(k_pool, dim3(4, NSEG), dim3(128), 0, stream,
                       ids, gate, x, segmax, segden, pooled);
    hipLaunchKernelGGL(k_head, dim3(NSEG), dim3(256), 0, stream,
                       pooled, pn_g, pn_b, mW1, mb1, mln_g, mln_b, mW2, mb2, logits);
}